// Round 4
// baseline (7668.688 us; speedup 1.0000x reference)
//
#include <hip/hip_runtime.h>
#include <hip/hip_cooperative_groups.h>

namespace cg = cooperative_groups;

typedef __attribute__((ext_vector_type(8))) short short8;   // 8 bf16 (4 VGPRs)
typedef __attribute__((ext_vector_type(4))) float f32x4;
typedef __attribute__((ext_vector_type(4))) float floatx4;
typedef __attribute__((ext_vector_type(4))) unsigned int uintx4;
typedef __attribute__((ext_vector_type(2))) unsigned int uintx2;

#define MFMA16(a, b, c) __builtin_amdgcn_mfma_f32_16x16x32_bf16(a, b, c, 0, 0, 0)

// B=64, S=512, V=32000, D=1024, H=1024, C=1000
#define SB_ROWS 32768   // S*B, row m = s*64 + b

__device__ __forceinline__ unsigned short f2bf(float f) {
  unsigned u = __float_as_uint(f);
  u += 0x7fffu + ((u >> 16) & 1u);          // RNE
  return (unsigned short)(u >> 16);
}
__device__ __forceinline__ float bf2f(short s) {
  return __uint_as_float(((unsigned)(unsigned short)s) << 16);
}
__device__ __forceinline__ float sigmoidf_(float x) {
  return 1.0f / (1.0f + __expf(-x));
}
__device__ __forceinline__ void gld_lds16(const void* g, void* l) {
  __builtin_amdgcn_global_load_lds(
      (const __attribute__((address_space(1))) unsigned int*)g,
      (__attribute__((address_space(3))) unsigned int*)l, 16, 0, 0);
}

// ---------------- f32 -> bf16 cast (n multiple of 4) ----------------
__global__ __launch_bounds__(256) void cast_bf16_k(const float* __restrict__ src,
                                                   short* __restrict__ dst, int n) {
  int i = (blockIdx.x * 256 + threadIdx.x) * 4;
  if (i >= n) return;
  floatx4 v = *(const floatx4*)(src + i);
  unsigned int lo = f2bf(v.x) | ((unsigned)f2bf(v.y) << 16);
  unsigned int hi = f2bf(v.z) | ((unsigned)f2bf(v.w) << 16);
  uintx2 o; o.x = lo; o.y = hi;
  *(uintx2*)(dst + i) = o;
}

// ---------------- embedding gather: xe16[s*64+b][d] = bf16(emb[x[b][s]][d]) ----------------
__global__ __launch_bounds__(128) void embed_gather(const int* __restrict__ x,
                                                    const float* __restrict__ emb,
                                                    short* __restrict__ xe16) {
  const int m = blockIdx.x;            // s*64 + b
  const int s = m >> 6, b = m & 63;
  const int idx = x[b * 512 + s];
  const int d0 = threadIdx.x * 8;
  const float* src = emb + (size_t)idx * 1024 + d0;
  floatx4 a = *(const floatx4*)src;
  floatx4 c = *(const floatx4*)(src + 4);
  uintx4 o;
  o.x = f2bf(a.x) | ((unsigned)f2bf(a.y) << 16);
  o.y = f2bf(a.z) | ((unsigned)f2bf(a.w) << 16);
  o.z = f2bf(c.x) | ((unsigned)f2bf(c.y) << 16);
  o.w = f2bf(c.z) | ((unsigned)f2bf(c.w) << 16);
  *(uintx4*)(xe16 + (size_t)m * 1024 + d0) = o;
}

// ---------------- batched projections: xfi[m][0:1024]=xe@Wf^T+bf, [1024:2048]=xe@Wi^T+bi ----
__global__ __launch_bounds__(256, 2) void gemm_xfi(const short* __restrict__ A,
                                                   const short* __restrict__ Wf,
                                                   const short* __restrict__ Wi,
                                                   const float* __restrict__ bfp,
                                                   const float* __restrict__ bip,
                                                   float* __restrict__ Cout) {
  __shared__ __align__(16) short As[128 * 64];
  __shared__ __align__(16) short Bs[128 * 64];
  const int tid = threadIdx.x;
  const int wave = tid >> 6, lane = tid & 63;
  const int quad = lane >> 4, l15 = lane & 15;
  const int nt = blockIdx.x & 15;
  const long m0 = (long)(blockIdx.x >> 4) * 128;
  const int n0 = nt * 128;
  const short* Bm = (n0 < 1024) ? Wf : Wi;
  const int nb = (n0 < 1024) ? n0 : n0 - 1024;
  const int wm = (wave >> 1) * 64, wn = (wave & 1) * 64;

  f32x4 acc[4][4] = {};
  const int cb = wave * 4;

  for (int k0 = 0; k0 < 1024; k0 += 64) {
    __syncthreads();
#pragma unroll
    for (int q = 0; q < 4; ++q) {
      int Cc = (cb + q) * 64 + lane;
      int row = Cc >> 3, slot = Cc & 7;
      int gk = k0 + ((slot ^ (row & 7)) << 3);
      gld_lds16(A + (m0 + row) * 1024 + gk, As + (size_t)(cb + q) * 512);
      gld_lds16(Bm + (long)(nb + row) * 1024 + gk, Bs + (size_t)(cb + q) * 512);
    }
    __syncthreads();
#pragma unroll
    for (int ks = 0; ks < 2; ++ks) {
      short8 av[4], bv[4];
      const int slin = ks * 4 + quad;
#pragma unroll
      for (int i = 0; i < 4; ++i) {
        int row = wm + i * 16 + l15;
        int slot = slin ^ (row & 7);
        av[i] = *(const short8*)&As[row * 64 + slot * 8];
      }
#pragma unroll
      for (int j = 0; j < 4; ++j) {
        int col = wn + j * 16 + l15;
        int slot = slin ^ (col & 7);
        bv[j] = *(const short8*)&Bs[col * 64 + slot * 8];
      }
#pragma unroll
      for (int i = 0; i < 4; ++i)
#pragma unroll
        for (int j = 0; j < 4; ++j) acc[i][j] = MFMA16(av[i], bv[j], acc[i][j]);
    }
  }
#pragma unroll
  for (int j = 0; j < 4; ++j) {
    int ng = n0 + wn + j * 16 + l15;
    float bias = (ng < 1024) ? bfp[ng] : bip[ng - 1024];
#pragma unroll
    for (int i = 0; i < 4; ++i)
#pragma unroll
      for (int r = 0; r < 4; ++r) {
        long m = m0 + wm + i * 16 + quad * 4 + r;
        Cout[m * 2048 + ng] = acc[i][j][r] + bias;
      }
  }
}

// ---------------- cooperative recurrence: 512 steps, 64 blocks x 256 thr ----------------
// U in LDS (R1-proven staging), h32 in registers (thread-local), h16 ping-pong global,
// software-pipelined A-loads (Abuf 2x8), input prefetch before cg grid sync.
__global__ __launch_bounds__(256, 1) void ran_scan(const float* __restrict__ xfi,
                                                   const short* __restrict__ xe16,
                                                   const short* __restrict__ Uf,
                                                   const short* __restrict__ Ui,
                                                   short* __restrict__ h16) {
  __shared__ __align__(16) short Us[2][16 * 1024];   // 64 KB
  const int tid = threadIdx.x;
  const int wave = tid >> 6, lane = tid & 63;
  const int quad = lane >> 4, l15 = lane & 15;
  const int c0 = blockIdx.x * 16;
  const int rw = wave * 16;
  const int colg = c0 + l15;

  // stage U rows c0..c0+15 for both gates; 16B-chunk XOR swizzle (verbatim R1)
#pragma unroll
  for (int g = 0; g < 2; ++g) {
    const short* U = g ? Ui : Uf;
    for (int it = 0; it < 8; ++it) {
      int Cc = it * 256 + tid;         // 0..2047
      int row = Cc >> 7;               // 0..15
      int slt = Cc & 127;
      int gsl = (slt & ~7) | ((slt ^ row) & 7);
      short8 v = *(const short8*)&U[(size_t)(c0 + row) * 1024 + gsl * 8];
      *(short8*)&Us[g][row * 1024 + slt * 8] = v;
    }
  }
  __syncthreads();

  cg::grid_group grid = cg::this_grid();

  float hreg[4] = {0.f, 0.f, 0.f, 0.f};   // fp32 h master (thread-local round-trip)
  float xfc[4], xic[4], xec[4];           // current-step inputs (prefetched)
#pragma unroll
  for (int r = 0; r < 4; ++r) {
    int rb = rw + quad * 4 + r;
    xfc[r] = xfi[(size_t)rb * 2048 + colg];
    xic[r] = xfi[(size_t)rb * 2048 + 1024 + colg];
    xec[r] = bf2f(xe16[(size_t)rb * 1024 + colg]);
  }

  for (int t = 0; t < 512; ++t) {
    const int rp = t & 1, wp = rp ^ 1;
    f32x4 af0 = {0.f, 0.f, 0.f, 0.f}, af1 = af0, ai0 = af0, ai1 = af0;
    if (t > 0) {
      // A = h16 rows rw..rw+15; pipeline global loads in 4 batches of 8 fragments
      const short* hrow = h16 + (size_t)rp * 65536 + (size_t)(rw + l15) * 1024 + quad * 8;
      short8 Abuf[2][8];
#pragma unroll
      for (int j = 0; j < 8; ++j) Abuf[0][j] = *(const short8*)(hrow + j * 32);
#pragma unroll
      for (int g = 0; g < 4; ++g) {
        const int cbi = g & 1, nbi = cbi ^ 1;
        if (g < 3) {
#pragma unroll
          for (int j = 0; j < 8; ++j)
            Abuf[nbi][j] = *(const short8*)(hrow + (g + 1) * 256 + j * 32);
        }
#pragma unroll
        for (int j = 0; j < 8; ++j) {
          const int kc = g * 8 + j;
          const int slin = kc * 4 + quad;
          const int slt = (slin & ~7) | ((slin ^ l15) & 7);
          short8 a = Abuf[cbi][j];
          short8 bfv = *(const short8*)&Us[0][l15 * 1024 + slt * 8];
          short8 biv = *(const short8*)&Us[1][l15 * 1024 + slt * 8];
          if (j & 1) { af1 = MFMA16(a, bfv, af1); ai1 = MFMA16(a, biv, ai1); }
          else       { af0 = MFMA16(a, bfv, af0); ai0 = MFMA16(a, biv, ai0); }
        }
      }
    }
    // gating + h update + h16 publish
    short* hw = h16 + (size_t)wp * 65536;
#pragma unroll
    for (int r = 0; r < 4; ++r) {
      int rb = rw + quad * 4 + r;                 // C row = quad*4+reg
      float fg = sigmoidf_(xfc[r] + af0[r] + af1[r]);
      float ig = sigmoidf_(xic[r] + ai0[r] + ai1[r]);
      float hn = fg * hreg[r] + ig * xec[r];
      hreg[r] = hn;
      hw[(size_t)rb * 1024 + colg] = (short)f2bf(hn);
    }
    if (t < 511) {
      // prefetch next step's h-independent inputs BEFORE the sync: loads fly
      // during the barrier drain/spin.
      const size_t mb = (size_t)(t + 1) * 64;
      float nxf[4], nxi[4], nxe[4];
#pragma unroll
      for (int r = 0; r < 4; ++r) {
        int rb = rw + quad * 4 + r;
        size_t mrow = mb + rb;
        nxf[r] = xfi[mrow * 2048 + colg];
        nxi[r] = xfi[mrow * 2048 + 1024 + colg];
        nxe[r] = bf2f(xe16[mrow * 1024 + colg]);
      }
      grid.sync();
#pragma unroll
      for (int r = 0; r < 4; ++r) { xfc[r] = nxf[r]; xic[r] = nxi[r]; xec[r] = nxe[r]; }
    }
  }
  // t=511 wrote buffer 0 -> consumed by fc_kernel (kernel boundary = full flush)
}

// ---------------- final FC: out[b][c] = h @ fc_w^T + fc_b (c < 1000) ----------------
__global__ __launch_bounds__(256) void fc_kernel(const short* __restrict__ h16,
                                                 const short* __restrict__ fcw16,
                                                 const float* __restrict__ fcb,
                                                 float* __restrict__ out) {
  const int tid = threadIdx.x;
  const int wave = tid >> 6, lane = tid & 63;
  const int quad = lane >> 4, l15 = lane & 15;
  const int c = blockIdx.x * 64 + wave * 16 + l15;
  f32x4 acc[4] = {};
#pragma unroll
  for (int kc = 0; kc < 32; ++kc) {
    int k = kc * 32 + quad * 8;
    short8 b = *(const short8*)&fcw16[(size_t)c * 1024 + k];
#pragma unroll
    for (int i = 0; i < 4; ++i) {
      short8 a = *(const short8*)&h16[(size_t)(i * 16 + l15) * 1024 + k];
      acc[i] = MFMA16(a, b, acc[i]);
    }
  }
  if (c < 1000) {
    float bias = fcb[c];
#pragma unroll
    for (int i = 0; i < 4; ++i)
#pragma unroll
      for (int r = 0; r < 4; ++r) {
        int m = i * 16 + quad * 4 + r;
        out[m * 1000 + c] = acc[i][r] + bias;
      }
  }
}

extern "C" void kernel_launch(void* const* d_in, const int* in_sizes, int n_in,
                              void* d_out, int out_size, void* d_ws, size_t ws_size,
                              hipStream_t stream) {
  const int* x = (const int*)d_in[0];
  const float* emb = (const float*)d_in[1];
  const float* Wf_w = (const float*)d_in[2];
  const float* Wf_b = (const float*)d_in[3];
  const float* Uf_w = (const float*)d_in[4];
  const float* Wi_w = (const float*)d_in[5];
  const float* Wi_b = (const float*)d_in[6];
  const float* Ui_w = (const float*)d_in[7];
  const float* fc_w = (const float*)d_in[8];
  const float* fc_b = (const float*)d_in[9];
  float* out = (float*)d_out;

  char* ws = (char*)d_ws;
  size_t off = 0;
  auto alloc = [&](size_t bytes) {
    char* p = ws + off;
    off += (bytes + 255) & ~(size_t)255;
    return p;
  };
  short* xe16 = (short*)alloc((size_t)SB_ROWS * 1024 * 2);       // 64 MB
  float* xfi  = (float*)alloc((size_t)SB_ROWS * 2048 * 4);       // 256 MB
  short* Wf16 = (short*)alloc(1024ull * 1024 * 2);
  short* Wi16 = (short*)alloc(1024ull * 1024 * 2);
  short* Uf16 = (short*)alloc(1024ull * 1024 * 2);
  short* Ui16 = (short*)alloc(1024ull * 1024 * 2);
  short* fcw16 = (short*)alloc(1024ull * 1024 * 2);
  short* h16 = (short*)alloc(2ull * 65536 * 2);                  // ping-pong bf16 h
  if (off > ws_size) return;

  cast_bf16_k<<<1024, 256, 0, stream>>>(Wf_w, Wf16, 1024 * 1024);
  cast_bf16_k<<<1024, 256, 0, stream>>>(Wi_w, Wi16, 1024 * 1024);
  cast_bf16_k<<<1024, 256, 0, stream>>>(Uf_w, Uf16, 1024 * 1024);
  cast_bf16_k<<<1024, 256, 0, stream>>>(Ui_w, Ui16, 1024 * 1024);
  cast_bf16_k<<<1000, 256, 0, stream>>>(fc_w, fcw16, 1000 * 1024);
  embed_gather<<<SB_ROWS, 128, 0, stream>>>(x, emb, xe16);
  gemm_xfi<<<(SB_ROWS / 128) * 16, 256, 0, stream>>>(xe16, Wf16, Wi16, Wf_b, Wi_b, xfi);

  const float* xfi_a = xfi;
  const short* xe_a = xe16;
  const short* uf_a = Uf16;
  const short* ui_a = Ui16;
  short* h16_a = h16;
  void* args[] = {(void*)&xfi_a, (void*)&xe_a, (void*)&uf_a,
                  (void*)&ui_a,  (void*)&h16_a};
  (void)hipLaunchCooperativeKernel((void*)ran_scan, dim3(64), dim3(256), args, 0, stream);

  // after t=511 (odd): final h is in buffer 0
  fc_kernel<<<16, 256, 0, stream>>>(h16, fcw16, fc_b, out);
}

// Round 5
// 5744.942 us; speedup vs baseline: 1.3349x; 1.3349x over previous
//
#include <hip/hip_runtime.h>
#include <hip/hip_cooperative_groups.h>

typedef __attribute__((ext_vector_type(8))) short short8;   // 8 bf16 (4 VGPRs)
typedef __attribute__((ext_vector_type(4))) float f32x4;
typedef __attribute__((ext_vector_type(4))) float floatx4;
typedef __attribute__((ext_vector_type(4))) unsigned int uintx4;
typedef __attribute__((ext_vector_type(2))) unsigned int uintx2;

#define MFMA16(a, b, c) __builtin_amdgcn_mfma_f32_16x16x32_bf16(a, b, c, 0, 0, 0)

// B=64, S=512, V=32000, D=1024, H=1024, C=1000
#define SB_ROWS 32768   // S*B, row m = s*64 + b

__device__ __forceinline__ unsigned short f2bf(float f) {
  unsigned u = __float_as_uint(f);
  u += 0x7fffu + ((u >> 16) & 1u);          // RNE
  return (unsigned short)(u >> 16);
}
__device__ __forceinline__ float bf2f(short s) {
  return __uint_as_float(((unsigned)(unsigned short)s) << 16);
}
__device__ __forceinline__ float sigmoidf_(float x) {
  return 1.0f / (1.0f + __expf(-x));
}
__device__ __forceinline__ void gld_lds16(const void* g, void* l) {
  __builtin_amdgcn_global_load_lds(
      (const __attribute__((address_space(1))) unsigned int*)g,
      (__attribute__((address_space(3))) unsigned int*)l, 16, 0, 0);
}

// ---------------- f32 -> bf16 cast (n multiple of 4) ----------------
__global__ __launch_bounds__(256) void cast_bf16_k(const float* __restrict__ src,
                                                   short* __restrict__ dst, int n) {
  int i = (blockIdx.x * 256 + threadIdx.x) * 4;
  if (i >= n) return;
  floatx4 v = *(const floatx4*)(src + i);
  unsigned int lo = f2bf(v.x) | ((unsigned)f2bf(v.y) << 16);
  unsigned int hi = f2bf(v.z) | ((unsigned)f2bf(v.w) << 16);
  uintx2 o; o.x = lo; o.y = hi;
  *(uintx2*)(dst + i) = o;
}

// ---------------- embedding gather: xe16[s*64+b][d] = bf16(emb[x[b][s]][d]) ----------------
__global__ __launch_bounds__(128) void embed_gather(const int* __restrict__ x,
                                                    const float* __restrict__ emb,
                                                    short* __restrict__ xe16) {
  const int m = blockIdx.x;            // s*64 + b
  const int s = m >> 6, b = m & 63;
  const int idx = x[b * 512 + s];
  const int d0 = threadIdx.x * 8;
  const float* src = emb + (size_t)idx * 1024 + d0;
  floatx4 a = *(const floatx4*)src;
  floatx4 c = *(const floatx4*)(src + 4);
  uintx4 o;
  o.x = f2bf(a.x) | ((unsigned)f2bf(a.y) << 16);
  o.y = f2bf(a.z) | ((unsigned)f2bf(a.w) << 16);
  o.z = f2bf(c.x) | ((unsigned)f2bf(c.y) << 16);
  o.w = f2bf(c.z) | ((unsigned)f2bf(c.w) << 16);
  *(uintx4*)(xe16 + (size_t)m * 1024 + d0) = o;
}

// ---------------- batched projections: xfi[m][0:1024]=xe@Wf^T+bf, [1024:2048]=xe@Wi^T+bi ----
__global__ __launch_bounds__(256, 2) void gemm_xfi(const short* __restrict__ A,
                                                   const short* __restrict__ Wf,
                                                   const short* __restrict__ Wi,
                                                   const float* __restrict__ bfp,
                                                   const float* __restrict__ bip,
                                                   float* __restrict__ Cout) {
  __shared__ __align__(16) short As[128 * 64];
  __shared__ __align__(16) short Bs[128 * 64];
  const int tid = threadIdx.x;
  const int wave = tid >> 6, lane = tid & 63;
  const int quad = lane >> 4, l15 = lane & 15;
  const int nt = blockIdx.x & 15;
  const long m0 = (long)(blockIdx.x >> 4) * 128;
  const int n0 = nt * 128;
  const short* Bm = (n0 < 1024) ? Wf : Wi;
  const int nb = (n0 < 1024) ? n0 : n0 - 1024;
  const int wm = (wave >> 1) * 64, wn = (wave & 1) * 64;

  f32x4 acc[4][4] = {};
  const int cb = wave * 4;

  for (int k0 = 0; k0 < 1024; k0 += 64) {
    __syncthreads();
#pragma unroll
    for (int q = 0; q < 4; ++q) {
      int Cc = (cb + q) * 64 + lane;
      int row = Cc >> 3, slot = Cc & 7;
      int gk = k0 + ((slot ^ (row & 7)) << 3);
      gld_lds16(A + (m0 + row) * 1024 + gk, As + (size_t)(cb + q) * 512);
      gld_lds16(Bm + (long)(nb + row) * 1024 + gk, Bs + (size_t)(cb + q) * 512);
    }
    __syncthreads();
#pragma unroll
    for (int ks = 0; ks < 2; ++ks) {
      short8 av[4], bv[4];
      const int slin = ks * 4 + quad;
#pragma unroll
      for (int i = 0; i < 4; ++i) {
        int row = wm + i * 16 + l15;
        int slot = slin ^ (row & 7);
        av[i] = *(const short8*)&As[row * 64 + slot * 8];
      }
#pragma unroll
      for (int j = 0; j < 4; ++j) {
        int col = wn + j * 16 + l15;
        int slot = slin ^ (col & 7);
        bv[j] = *(const short8*)&Bs[col * 64 + slot * 8];
      }
#pragma unroll
      for (int i = 0; i < 4; ++i)
#pragma unroll
        for (int j = 0; j < 4; ++j) acc[i][j] = MFMA16(av[i], bv[j], acc[i][j]);
    }
  }
#pragma unroll
  for (int j = 0; j < 4; ++j) {
    int ng = n0 + wn + j * 16 + l15;
    float bias = (ng < 1024) ? bfp[ng] : bip[ng - 1024];
#pragma unroll
    for (int i = 0; i < 4; ++i)
#pragma unroll
      for (int r = 0; r < 4; ++r) {
        long m = m0 + wm + i * 16 + quad * 4 + r;
        Cout[m * 2048 + ng] = acc[i][j][r] + bias;
      }
  }
}

// ---------------- cooperative recurrence: 512 steps, 64 blocks x 256 thr ----------------
// R4 structure (U in LDS, hreg thread-local, pipelined A-loads, prefetch-before-sync),
// with cg::grid.sync() (~14us/step floor) replaced by a lean per-step-counter barrier:
//   __syncthreads (drain stores to XCD L2) -> tid0 RELEASE fetch_add (agent: wbl2 + LLC
//   atomic) -> tid0 relaxed spin (LLC loads, s_sleep backoff) -> __syncthreads ->
//   block-wide ACQUIRE fence (agent: L1/L2 inv).
__global__ __launch_bounds__(256, 1) void ran_scan(const float* __restrict__ xfi,
                                                   const short* __restrict__ xe16,
                                                   const short* __restrict__ Uf,
                                                   const short* __restrict__ Ui,
                                                   short* __restrict__ h16,
                                                   unsigned* __restrict__ cnt) {
  __shared__ __align__(16) short Us[2][16 * 1024];   // 64 KB
  const int tid = threadIdx.x;
  const int wave = tid >> 6, lane = tid & 63;
  const int quad = lane >> 4, l15 = lane & 15;
  const int c0 = blockIdx.x * 16;
  const int rw = wave * 16;
  const int colg = c0 + l15;

  // stage U rows c0..c0+15 for both gates; 16B-chunk XOR swizzle (verbatim R1/R4)
#pragma unroll
  for (int g = 0; g < 2; ++g) {
    const short* U = g ? Ui : Uf;
    for (int it = 0; it < 8; ++it) {
      int Cc = it * 256 + tid;         // 0..2047
      int row = Cc >> 7;               // 0..15
      int slt = Cc & 127;
      int gsl = (slt & ~7) | ((slt ^ row) & 7);
      short8 v = *(const short8*)&U[(size_t)(c0 + row) * 1024 + gsl * 8];
      *(short8*)&Us[g][row * 1024 + slt * 8] = v;
    }
  }
  __syncthreads();

  float hreg[4] = {0.f, 0.f, 0.f, 0.f};   // fp32 h master (thread-local round-trip)
  float xfc[4], xic[4], xec[4];           // current-step inputs (prefetched)
#pragma unroll
  for (int r = 0; r < 4; ++r) {
    int rb = rw + quad * 4 + r;
    xfc[r] = xfi[(size_t)rb * 2048 + colg];
    xic[r] = xfi[(size_t)rb * 2048 + 1024 + colg];
    xec[r] = bf2f(xe16[(size_t)rb * 1024 + colg]);
  }

  for (int t = 0; t < 512; ++t) {
    const int rp = t & 1, wp = rp ^ 1;
    f32x4 af0 = {0.f, 0.f, 0.f, 0.f}, af1 = af0, ai0 = af0, ai1 = af0;
    if (t > 0) {
      // A = h16 rows rw..rw+15; pipeline global loads in 4 batches of 8 fragments
      const short* hrow = h16 + (size_t)rp * 65536 + (size_t)(rw + l15) * 1024 + quad * 8;
      short8 Abuf[2][8];
#pragma unroll
      for (int j = 0; j < 8; ++j) Abuf[0][j] = *(const short8*)(hrow + j * 32);
#pragma unroll
      for (int g = 0; g < 4; ++g) {
        const int cbi = g & 1, nbi = cbi ^ 1;
        if (g < 3) {
#pragma unroll
          for (int j = 0; j < 8; ++j)
            Abuf[nbi][j] = *(const short8*)(hrow + (g + 1) * 256 + j * 32);
        }
#pragma unroll
        for (int j = 0; j < 8; ++j) {
          const int kc = g * 8 + j;
          const int slin = kc * 4 + quad;
          const int slt = (slin & ~7) | ((slin ^ l15) & 7);
          short8 a = Abuf[cbi][j];
          short8 bfv = *(const short8*)&Us[0][l15 * 1024 + slt * 8];
          short8 biv = *(const short8*)&Us[1][l15 * 1024 + slt * 8];
          if (j & 1) { af1 = MFMA16(a, bfv, af1); ai1 = MFMA16(a, biv, ai1); }
          else       { af0 = MFMA16(a, bfv, af0); ai0 = MFMA16(a, biv, ai0); }
        }
      }
    }
    // gating + h update + h16 publish
    short* hw = h16 + (size_t)wp * 65536;
#pragma unroll
    for (int r = 0; r < 4; ++r) {
      int rb = rw + quad * 4 + r;                 // C row = quad*4+reg
      float fg = sigmoidf_(xfc[r] + af0[r] + af1[r]);
      float ig = sigmoidf_(xic[r] + ai0[r] + ai1[r]);
      float hn = fg * hreg[r] + ig * xec[r];
      hreg[r] = hn;
      hw[(size_t)rb * 1024 + colg] = (short)f2bf(hn);
    }
    if (t < 511) {
      // prefetch next step's h-independent inputs BEFORE the barrier
      const size_t mb = (size_t)(t + 1) * 64;
      float nxf[4], nxi[4], nxe[4];
#pragma unroll
      for (int r = 0; r < 4; ++r) {
        int rb = rw + quad * 4 + r;
        size_t mrow = mb + rb;
        nxf[r] = xfi[mrow * 2048 + colg];
        nxi[r] = xfi[mrow * 2048 + 1024 + colg];
        nxe[r] = bf2f(xe16[mrow * 1024 + colg]);
      }
      // ---- custom grid barrier (per-step counter, no generations) ----
      __syncthreads();   // every wave drains its h16 stores (vmcnt 0) to XCD L2
      if (tid == 0) {
        __hip_atomic_fetch_add(&cnt[t], 1u, __ATOMIC_RELEASE,
                               __HIP_MEMORY_SCOPE_AGENT);      // wbl2 + LLC-point add
        while (__hip_atomic_load(&cnt[t], __ATOMIC_RELAXED,
                                 __HIP_MEMORY_SCOPE_AGENT) < 64u)
          __builtin_amdgcn_s_sleep(1);
      }
      __syncthreads();
      __builtin_amdgcn_fence(__ATOMIC_ACQUIRE, "agent");       // inv L1/L2 before h reads
#pragma unroll
      for (int r = 0; r < 4; ++r) { xfc[r] = nxf[r]; xic[r] = nxi[r]; xec[r] = nxe[r]; }
    }
  }
  // t=511 wrote buffer 0 -> consumed by fc_kernel (kernel boundary = full flush)
}

// ---------------- final FC: out[b][c] = h @ fc_w^T + fc_b (c < 1000) ----------------
__global__ __launch_bounds__(256) void fc_kernel(const short* __restrict__ h16,
                                                 const short* __restrict__ fcw16,
                                                 const float* __restrict__ fcb,
                                                 float* __restrict__ out) {
  const int tid = threadIdx.x;
  const int wave = tid >> 6, lane = tid & 63;
  const int quad = lane >> 4, l15 = lane & 15;
  const int c = blockIdx.x * 64 + wave * 16 + l15;
  f32x4 acc[4] = {};
#pragma unroll
  for (int kc = 0; kc < 32; ++kc) {
    int k = kc * 32 + quad * 8;
    short8 b = *(const short8*)&fcw16[(size_t)c * 1024 + k];
#pragma unroll
    for (int i = 0; i < 4; ++i) {
      short8 a = *(const short8*)&h16[(size_t)(i * 16 + l15) * 1024 + k];
      acc[i] = MFMA16(a, b, acc[i]);
    }
  }
  if (c < 1000) {
    float bias = fcb[c];
#pragma unroll
    for (int i = 0; i < 4; ++i)
#pragma unroll
      for (int r = 0; r < 4; ++r) {
        int m = i * 16 + quad * 4 + r;
        out[m * 1000 + c] = acc[i][r] + bias;
      }
  }
}

extern "C" void kernel_launch(void* const* d_in, const int* in_sizes, int n_in,
                              void* d_out, int out_size, void* d_ws, size_t ws_size,
                              hipStream_t stream) {
  const int* x = (const int*)d_in[0];
  const float* emb = (const float*)d_in[1];
  const float* Wf_w = (const float*)d_in[2];
  const float* Wf_b = (const float*)d_in[3];
  const float* Uf_w = (const float*)d_in[4];
  const float* Wi_w = (const float*)d_in[5];
  const float* Wi_b = (const float*)d_in[6];
  const float* Ui_w = (const float*)d_in[7];
  const float* fc_w = (const float*)d_in[8];
  const float* fc_b = (const float*)d_in[9];
  float* out = (float*)d_out;

  char* ws = (char*)d_ws;
  size_t off = 0;
  auto alloc = [&](size_t bytes) {
    char* p = ws + off;
    off += (bytes + 255) & ~(size_t)255;
    return p;
  };
  short* xe16 = (short*)alloc((size_t)SB_ROWS * 1024 * 2);       // 64 MB
  float* xfi  = (float*)alloc((size_t)SB_ROWS * 2048 * 4);       // 256 MB
  short* Wf16 = (short*)alloc(1024ull * 1024 * 2);
  short* Wi16 = (short*)alloc(1024ull * 1024 * 2);
  short* Uf16 = (short*)alloc(1024ull * 1024 * 2);
  short* Ui16 = (short*)alloc(1024ull * 1024 * 2);
  short* fcw16 = (short*)alloc(1024ull * 1024 * 2);
  short* h16 = (short*)alloc(2ull * 65536 * 2);                  // ping-pong bf16 h
  unsigned* cnt = (unsigned*)alloc(512 * sizeof(unsigned));      // per-step barrier counters
  if (off > ws_size) return;

  hipMemsetAsync((void*)cnt, 0, 512 * sizeof(unsigned), stream);
  cast_bf16_k<<<1024, 256, 0, stream>>>(Wf_w, Wf16, 1024 * 1024);
  cast_bf16_k<<<1024, 256, 0, stream>>>(Wi_w, Wi16, 1024 * 1024);
  cast_bf16_k<<<1024, 256, 0, stream>>>(Uf_w, Uf16, 1024 * 1024);
  cast_bf16_k<<<1024, 256, 0, stream>>>(Ui_w, Ui16, 1024 * 1024);
  cast_bf16_k<<<1000, 256, 0, stream>>>(fc_w, fcw16, 1000 * 1024);
  embed_gather<<<SB_ROWS, 128, 0, stream>>>(x, emb, xe16);
  gemm_xfi<<<(SB_ROWS / 128) * 16, 256, 0, stream>>>(xe16, Wf16, Wi16, Wf_b, Wi_b, xfi);

  const float* xfi_a = xfi;
  const short* xe_a = xe16;
  const short* uf_a = Uf16;
  const short* ui_a = Ui16;
  short* h16_a = h16;
  unsigned* cnt_a = cnt;
  void* args[] = {(void*)&xfi_a, (void*)&xe_a, (void*)&uf_a,
                  (void*)&ui_a,  (void*)&h16_a, (void*)&cnt_a};
  (void)hipLaunchCooperativeKernel((void*)ran_scan, dim3(64), dim3(256), args, 0, stream);

  // after t=511 (odd): final h is in buffer 0
  fc_kernel<<<16, 256, 0, stream>>>(h16, fcw16, fc_b, out);
}

// Round 6
// 5029.586 us; speedup vs baseline: 1.5247x; 1.1422x over previous
//
#include <hip/hip_runtime.h>
#include <hip/hip_cooperative_groups.h>

typedef __attribute__((ext_vector_type(8))) short short8;   // 8 bf16 (4 VGPRs)
typedef __attribute__((ext_vector_type(4))) float f32x4;
typedef __attribute__((ext_vector_type(4))) float floatx4;
typedef __attribute__((ext_vector_type(4))) unsigned int uintx4;
typedef __attribute__((ext_vector_type(2))) unsigned int uintx2;

#define MFMA16(a, b, c) __builtin_amdgcn_mfma_f32_16x16x32_bf16(a, b, c, 0, 0, 0)

// B=64, S=512, V=32000, D=1024, H=1024, C=1000
#define SB_ROWS 32768   // S*B, row m = s*64 + b

#define AT_LOAD_U64(p)  __hip_atomic_load((p), __ATOMIC_RELAXED, __HIP_MEMORY_SCOPE_AGENT)
#define AT_STORE_U32(p, v) __hip_atomic_store((p), (v), __ATOMIC_RELAXED, __HIP_MEMORY_SCOPE_AGENT)

__device__ __forceinline__ unsigned short f2bf(float f) {
  unsigned u = __float_as_uint(f);
  u += 0x7fffu + ((u >> 16) & 1u);          // RNE
  return (unsigned short)(u >> 16);
}
__device__ __forceinline__ float bf2f(short s) {
  return __uint_as_float(((unsigned)(unsigned short)s) << 16);
}
__device__ __forceinline__ float sigmoidf_(float x) {
  return 1.0f / (1.0f + __expf(-x));
}
__device__ __forceinline__ void gld_lds16(const void* g, void* l) {
  __builtin_amdgcn_global_load_lds(
      (const __attribute__((address_space(1))) unsigned int*)g,
      (__attribute__((address_space(3))) unsigned int*)l, 16, 0, 0);
}

// ---------------- f32 -> bf16 cast (n multiple of 4) ----------------
__global__ __launch_bounds__(256) void cast_bf16_k(const float* __restrict__ src,
                                                   short* __restrict__ dst, int n) {
  int i = (blockIdx.x * 256 + threadIdx.x) * 4;
  if (i >= n) return;
  floatx4 v = *(const floatx4*)(src + i);
  unsigned int lo = f2bf(v.x) | ((unsigned)f2bf(v.y) << 16);
  unsigned int hi = f2bf(v.z) | ((unsigned)f2bf(v.w) << 16);
  uintx2 o; o.x = lo; o.y = hi;
  *(uintx2*)(dst + i) = o;
}

// ---------------- embedding gather: xe16[s*64+b][d] = bf16(emb[x[b][s]][d]) ----------------
__global__ __launch_bounds__(128) void embed_gather(const int* __restrict__ x,
                                                    const float* __restrict__ emb,
                                                    short* __restrict__ xe16) {
  const int m = blockIdx.x;            // s*64 + b
  const int s = m >> 6, b = m & 63;
  const int idx = x[b * 512 + s];
  const int d0 = threadIdx.x * 8;
  const float* src = emb + (size_t)idx * 1024 + d0;
  floatx4 a = *(const floatx4*)src;
  floatx4 c = *(const floatx4*)(src + 4);
  uintx4 o;
  o.x = f2bf(a.x) | ((unsigned)f2bf(a.y) << 16);
  o.y = f2bf(a.z) | ((unsigned)f2bf(a.w) << 16);
  o.z = f2bf(c.x) | ((unsigned)f2bf(c.y) << 16);
  o.w = f2bf(c.z) | ((unsigned)f2bf(c.w) << 16);
  *(uintx4*)(xe16 + (size_t)m * 1024 + d0) = o;
}

// ---------------- batched projections: xfi[m][0:1024]=xe@Wf^T+bf, [1024:2048]=xe@Wi^T+bi ----
__global__ __launch_bounds__(256, 2) void gemm_xfi(const short* __restrict__ A,
                                                   const short* __restrict__ Wf,
                                                   const short* __restrict__ Wi,
                                                   const float* __restrict__ bfp,
                                                   const float* __restrict__ bip,
                                                   float* __restrict__ Cout) {
  __shared__ __align__(16) short As[128 * 64];
  __shared__ __align__(16) short Bs[128 * 64];
  const int tid = threadIdx.x;
  const int wave = tid >> 6, lane = tid & 63;
  const int quad = lane >> 4, l15 = lane & 15;
  const int nt = blockIdx.x & 15;
  const long m0 = (long)(blockIdx.x >> 4) * 128;
  const int n0 = nt * 128;
  const short* Bm = (n0 < 1024) ? Wf : Wi;
  const int nb = (n0 < 1024) ? n0 : n0 - 1024;
  const int wm = (wave >> 1) * 64, wn = (wave & 1) * 64;

  f32x4 acc[4][4] = {};
  const int cb = wave * 4;

  for (int k0 = 0; k0 < 1024; k0 += 64) {
    __syncthreads();
#pragma unroll
    for (int q = 0; q < 4; ++q) {
      int Cc = (cb + q) * 64 + lane;
      int row = Cc >> 3, slot = Cc & 7;
      int gk = k0 + ((slot ^ (row & 7)) << 3);
      gld_lds16(A + (m0 + row) * 1024 + gk, As + (size_t)(cb + q) * 512);
      gld_lds16(Bm + (long)(nb + row) * 1024 + gk, Bs + (size_t)(cb + q) * 512);
    }
    __syncthreads();
#pragma unroll
    for (int ks = 0; ks < 2; ++ks) {
      short8 av[4], bv[4];
      const int slin = ks * 4 + quad;
#pragma unroll
      for (int i = 0; i < 4; ++i) {
        int row = wm + i * 16 + l15;
        int slot = slin ^ (row & 7);
        av[i] = *(const short8*)&As[row * 64 + slot * 8];
      }
#pragma unroll
      for (int j = 0; j < 4; ++j) {
        int col = wn + j * 16 + l15;
        int slot = slin ^ (col & 7);
        bv[j] = *(const short8*)&Bs[col * 64 + slot * 8];
      }
#pragma unroll
      for (int i = 0; i < 4; ++i)
#pragma unroll
        for (int j = 0; j < 4; ++j) acc[i][j] = MFMA16(av[i], bv[j], acc[i][j]);
    }
  }
#pragma unroll
  for (int j = 0; j < 4; ++j) {
    int ng = n0 + wn + j * 16 + l15;
    float bias = (ng < 1024) ? bfp[ng] : bip[ng - 1024];
#pragma unroll
    for (int i = 0; i < 4; ++i)
#pragma unroll
      for (int r = 0; r < 4; ++r) {
        long m = m0 + wm + i * 16 + quad * 4 + r;
        Cout[m * 2048 + ng] = acc[i][j][r] + bias;
      }
  }
}

// ---------------- cooperative recurrence: 512 steps, 64 blocks x 256 thr ----------------
// R5 structure, but ALL h16 traffic is agent-scope relaxed atomics (sc0/sc1: per-access
// coherent at LLC) so the grid barrier needs NO fences / cache walks:
//   __syncthreads (vmcnt0 = write-through stores ack'd at LLC) -> tid0 relaxed
//   fetch_add -> tid0 relaxed spin -> __syncthreads. Loads read LLC directly.
__global__ __launch_bounds__(256, 1) void ran_scan(const float* __restrict__ xfi,
                                                   const short* __restrict__ xe16,
                                                   const short* __restrict__ Uf,
                                                   const short* __restrict__ Ui,
                                                   short* __restrict__ h16,
                                                   unsigned* __restrict__ cnt) {
  __shared__ __align__(16) short Us[2][16 * 1024];   // 64 KB
  const int tid = threadIdx.x;
  const int wave = tid >> 6, lane = tid & 63;
  const int quad = lane >> 4, l15 = lane & 15;
  const int c0 = blockIdx.x * 16;
  const int rw = wave * 16;
  const int colg = c0 + l15;

  // stage U rows c0..c0+15 for both gates; 16B-chunk XOR swizzle (verbatim R1/R4)
#pragma unroll
  for (int g = 0; g < 2; ++g) {
    const short* U = g ? Ui : Uf;
    for (int it = 0; it < 8; ++it) {
      int Cc = it * 256 + tid;         // 0..2047
      int row = Cc >> 7;               // 0..15
      int slt = Cc & 127;
      int gsl = (slt & ~7) | ((slt ^ row) & 7);
      short8 v = *(const short8*)&U[(size_t)(c0 + row) * 1024 + gsl * 8];
      *(short8*)&Us[g][row * 1024 + slt * 8] = v;
    }
  }
  __syncthreads();

  float hreg[4] = {0.f, 0.f, 0.f, 0.f};   // fp32 h master (thread-local round-trip)
  float xfc[4], xic[4], xec[4];           // current-step inputs (prefetched)
#pragma unroll
  for (int r = 0; r < 4; ++r) {
    int rb = rw + quad * 4 + r;
    xfc[r] = xfi[(size_t)rb * 2048 + colg];
    xic[r] = xfi[(size_t)rb * 2048 + 1024 + colg];
    xec[r] = bf2f(xe16[(size_t)rb * 1024 + colg]);
  }

  union U8 { unsigned long long q[2]; short8 s; };

  for (int t = 0; t < 512; ++t) {
    const int rp = t & 1, wp = rp ^ 1;
    f32x4 af0 = {0.f, 0.f, 0.f, 0.f}, af1 = af0, ai0 = af0, ai1 = af0;
    if (t > 0) {
      // A = h16 rows rw..rw+15 via coherent 8B atomic loads (LLC), pipelined 4x8
      const unsigned long long* hq =
          (const unsigned long long*)(h16 + (size_t)rp * 65536);
      const size_t fb = (size_t)(rw + l15) * 256 + quad * 2;   // u64 units
      unsigned long long Aq[2][16];
#pragma unroll
      for (int j = 0; j < 8; ++j) {
        Aq[0][2 * j]     = AT_LOAD_U64(hq + fb + j * 8);
        Aq[0][2 * j + 1] = AT_LOAD_U64(hq + fb + j * 8 + 1);
      }
#pragma unroll
      for (int g = 0; g < 4; ++g) {
        const int cbi = g & 1, nbi = cbi ^ 1;
        if (g < 3) {
#pragma unroll
          for (int j = 0; j < 8; ++j) {
            Aq[nbi][2 * j]     = AT_LOAD_U64(hq + fb + (g + 1) * 64 + j * 8);
            Aq[nbi][2 * j + 1] = AT_LOAD_U64(hq + fb + (g + 1) * 64 + j * 8 + 1);
          }
        }
#pragma unroll
        for (int j = 0; j < 8; ++j) {
          const int kc = g * 8 + j;
          const int slin = kc * 4 + quad;
          const int slt = (slin & ~7) | ((slin ^ l15) & 7);
          U8 u; u.q[0] = Aq[cbi][2 * j]; u.q[1] = Aq[cbi][2 * j + 1];
          short8 a = u.s;
          short8 bfv = *(const short8*)&Us[0][l15 * 1024 + slt * 8];
          short8 biv = *(const short8*)&Us[1][l15 * 1024 + slt * 8];
          if (j & 1) { af1 = MFMA16(a, bfv, af1); ai1 = MFMA16(a, biv, ai1); }
          else       { af0 = MFMA16(a, bfv, af0); ai0 = MFMA16(a, biv, ai0); }
        }
      }
    }
    // gating + h update
    unsigned short hb[4];
#pragma unroll
    for (int r = 0; r < 4; ++r) {
      float fg = sigmoidf_(xfc[r] + af0[r] + af1[r]);
      float ig = sigmoidf_(xic[r] + ai0[r] + ai1[r]);
      float hn = fg * hreg[r] + ig * xec[r];
      hreg[r] = hn;
      hb[r] = f2bf(hn);
    }
    // publish h16 as coherent 32-bit stores: lane-xor pairs adjacent columns.
    // even l15 stores rows {quad*4+0,+1}, odd l15 stores rows {quad*4+2,+3} of the pair.
    {
      unsigned* hwp = (unsigned*)(h16 + (size_t)wp * 65536);
      unsigned p01 = hb[0] | ((unsigned)hb[1] << 16);
      unsigned p23 = hb[2] | ((unsigned)hb[3] << 16);
      unsigned q01 = (unsigned)__shfl_xor((int)p01, 1, 64);
      unsigned q23 = (unsigned)__shfl_xor((int)p23, 1, 64);
      const int cph = (c0 + (l15 & ~1)) >> 1;   // dword col index
      const int rbase = rw + quad * 4;
      if (!(l15 & 1)) {
        unsigned dw0 = (p01 & 0xffffu) | (q01 << 16);
        unsigned dw1 = (p01 >> 16) | (q01 & 0xffff0000u);
        AT_STORE_U32(hwp + (size_t)(rbase + 0) * 512 + cph, dw0);
        AT_STORE_U32(hwp + (size_t)(rbase + 1) * 512 + cph, dw1);
      } else {
        unsigned dw2 = (q23 & 0xffffu) | (p23 << 16);
        unsigned dw3 = (q23 >> 16) | (p23 & 0xffff0000u);
        AT_STORE_U32(hwp + (size_t)(rbase + 2) * 512 + cph, dw2);
        AT_STORE_U32(hwp + (size_t)(rbase + 3) * 512 + cph, dw3);
      }
    }
    if (t < 511) {
      // prefetch next step's h-independent inputs BEFORE the barrier
      const size_t mb = (size_t)(t + 1) * 64;
      float nxf[4], nxi[4], nxe[4];
#pragma unroll
      for (int r = 0; r < 4; ++r) {
        int rb = rw + quad * 4 + r;
        size_t mrow = mb + rb;
        nxf[r] = xfi[mrow * 2048 + colg];
        nxi[r] = xfi[mrow * 2048 + 1024 + colg];
        nxe[r] = bf2f(xe16[mrow * 1024 + colg]);
      }
      // ---- fence-free grid barrier (per-step counter) ----
      __syncthreads();   // vmcnt(0): all coherent stores ack'd at LLC
      if (tid == 0) {
        __hip_atomic_fetch_add(&cnt[t], 1u, __ATOMIC_RELAXED,
                               __HIP_MEMORY_SCOPE_AGENT);
        while (__hip_atomic_load(&cnt[t], __ATOMIC_RELAXED,
                                 __HIP_MEMORY_SCOPE_AGENT) < 64u)
          __builtin_amdgcn_s_sleep(1);
      }
      __syncthreads();
#pragma unroll
      for (int r = 0; r < 4; ++r) { xfc[r] = nxf[r]; xic[r] = nxi[r]; xec[r] = nxe[r]; }
    }
  }
  // t=511 wrote buffer 0 (write-through, at LLC). fc_kernel launch's implicit
  // acquire (kernel boundary) makes it visible — same mechanism as gemm->scan.
}

// ---------------- final FC: out[b][c] = h @ fc_w^T + fc_b (c < 1000) ----------------
__global__ __launch_bounds__(256) void fc_kernel(const short* __restrict__ h16,
                                                 const short* __restrict__ fcw16,
                                                 const float* __restrict__ fcb,
                                                 float* __restrict__ out) {
  const int tid = threadIdx.x;
  const int wave = tid >> 6, lane = tid & 63;
  const int quad = lane >> 4, l15 = lane & 15;
  const int c = blockIdx.x * 64 + wave * 16 + l15;
  f32x4 acc[4] = {};
#pragma unroll
  for (int kc = 0; kc < 32; ++kc) {
    int k = kc * 32 + quad * 8;
    short8 b = *(const short8*)&fcw16[(size_t)c * 1024 + k];
#pragma unroll
    for (int i = 0; i < 4; ++i) {
      short8 a = *(const short8*)&h16[(size_t)(i * 16 + l15) * 1024 + k];
      acc[i] = MFMA16(a, b, acc[i]);
    }
  }
  if (c < 1000) {
    float bias = fcb[c];
#pragma unroll
    for (int i = 0; i < 4; ++i)
#pragma unroll
      for (int r = 0; r < 4; ++r) {
        int m = i * 16 + quad * 4 + r;
        out[m * 1000 + c] = acc[i][r] + bias;
      }
  }
}

extern "C" void kernel_launch(void* const* d_in, const int* in_sizes, int n_in,
                              void* d_out, int out_size, void* d_ws, size_t ws_size,
                              hipStream_t stream) {
  const int* x = (const int*)d_in[0];
  const float* emb = (const float*)d_in[1];
  const float* Wf_w = (const float*)d_in[2];
  const float* Wf_b = (const float*)d_in[3];
  const float* Uf_w = (const float*)d_in[4];
  const float* Wi_w = (const float*)d_in[5];
  const float* Wi_b = (const float*)d_in[6];
  const float* Ui_w = (const float*)d_in[7];
  const float* fc_w = (const float*)d_in[8];
  const float* fc_b = (const float*)d_in[9];
  float* out = (float*)d_out;

  char* ws = (char*)d_ws;
  size_t off = 0;
  auto alloc = [&](size_t bytes) {
    char* p = ws + off;
    off += (bytes + 255) & ~(size_t)255;
    return p;
  };
  short* xe16 = (short*)alloc((size_t)SB_ROWS * 1024 * 2);       // 64 MB
  float* xfi  = (float*)alloc((size_t)SB_ROWS * 2048 * 4);       // 256 MB
  short* Wf16 = (short*)alloc(1024ull * 1024 * 2);
  short* Wi16 = (short*)alloc(1024ull * 1024 * 2);
  short* Uf16 = (short*)alloc(1024ull * 1024 * 2);
  short* Ui16 = (short*)alloc(1024ull * 1024 * 2);
  short* fcw16 = (short*)alloc(1024ull * 1024 * 2);
  short* h16 = (short*)alloc(2ull * 65536 * 2);                  // ping-pong bf16 h
  unsigned* cnt = (unsigned*)alloc(512 * sizeof(unsigned));      // per-step barrier counters
  if (off > ws_size) return;

  hipMemsetAsync((void*)cnt, 0, 512 * sizeof(unsigned), stream);
  cast_bf16_k<<<1024, 256, 0, stream>>>(Wf_w, Wf16, 1024 * 1024);
  cast_bf16_k<<<1024, 256, 0, stream>>>(Wi_w, Wi16, 1024 * 1024);
  cast_bf16_k<<<1024, 256, 0, stream>>>(Uf_w, Uf16, 1024 * 1024);
  cast_bf16_k<<<1024, 256, 0, stream>>>(Ui_w, Ui16, 1024 * 1024);
  cast_bf16_k<<<1000, 256, 0, stream>>>(fc_w, fcw16, 1000 * 1024);
  embed_gather<<<SB_ROWS, 128, 0, stream>>>(x, emb, xe16);
  gemm_xfi<<<(SB_ROWS / 128) * 16, 256, 0, stream>>>(xe16, Wf16, Wi16, Wf_b, Wi_b, xfi);

  const float* xfi_a = xfi;
  const short* xe_a = xe16;
  const short* uf_a = Uf16;
  const short* ui_a = Ui16;
  short* h16_a = h16;
  unsigned* cnt_a = cnt;
  void* args[] = {(void*)&xfi_a, (void*)&xe_a, (void*)&uf_a,
                  (void*)&ui_a,  (void*)&h16_a, (void*)&cnt_a};
  (void)hipLaunchCooperativeKernel((void*)ran_scan, dim3(64), dim3(256), args, 0, stream);

  // after t=511 (odd): final h is in buffer 0
  fc_kernel<<<16, 256, 0, stream>>>(h16, fcw16, fc_b, out);
}